// Round 6
// baseline (30.095 us; speedup 1.0000x reference)
//
#include <hip/hip_runtime.h>

// GSA loss: pred [B=2,1,64,64] fp32, token [B,4096,4096] fp32 -> scalar fp32.
// loss = 2 - s_fa/s_f - s_bb/s_b with
//   T   = sum t_ij
//   s_f = sum p_i t_ij        (row-weighted)
//   s_c = sum t_ij p_j        (col-weighted; token NOT symmetric)
//   s_fa= sum p_i t_ij p_j
//   s_b = T - s_f
//   s_bb= T - s_f - s_c + s_fa
//
// R2: killed same-address fp64 atomics (117.9 -> 29.6 us).
// R3/R4: load-hoist + sched_barrier on the one-shot structure — NEUTRAL.
//   A one-shot wave pays full memory latency once and has nothing of its own
//   to overlap it; hints can't fix dataflow.
// R5: persistent waves + explicit double-buffered row pipeline. 2048 waves x
//   4 rows each; load row r+1 while computing row r. Loop dependence forces
//   load issue ahead of compute. launch_bounds(256,2): ~150 VGPR needed for
//   two 16xfloat4 buffers, 2 blocks/CU, 128 KB in flight per CU.

#define HW   4096
#define HW4  1024   // HW / 4
#define NBLK 512
#define RPW  4      // rows per wave; 512 blk * 4 waves * 4 rows = 8192 = B*HW

struct alignas(32) D4 { double t, f, c, fa; };

__global__ __launch_bounds__(256, 2) void gsa_partial(
    const float* __restrict__ pred,
    const float* __restrict__ token,
    D4* __restrict__ part)           // part[NBLK]
{
    __shared__ float4 pj_lds[HW4];   // 16 KB: pred row for this batch
    __shared__ double sm[4][4];

    const float4* __restrict__ tok4  = (const float4*)token;
    const float4* __restrict__ pred4 = (const float4*)pred;

    const int bid  = blockIdx.x;         // 0..511
    const int wave = threadIdx.x >> 6;
    const int lane = threadIdx.x & 63;
    const int gw   = bid * 4 + wave;     // global wave 0..2047
    const int row0 = gw * RPW;           // 4 consecutive rows, batch-aligned
    const int b    = row0 >> 12;

    // stage pred[b,:] once per block (overlaps first row loads' latency below)
    for (int k = threadIdx.x; k < HW4; k += 256)
        pj_lds[k] = pred4[b * HW4 + k];

    // wave-uniform pi for all 4 rows (scalar loads, hoisted off critical path)
    float pi_r[RPW];
#pragma unroll
    for (int r = 0; r < RPW; ++r)
        pi_r[r] = pred[row0 + r];

    // prologue: fill buffer A with row 0
    float4 A[16], Bv[16];
    {
        const float4* __restrict__ rp = tok4 + (size_t)row0 * HW4;
#pragma unroll
        for (int u = 0; u < 16; ++u)
            A[u] = rp[u * 64 + lane];
    }

    __syncthreads();                     // pred staged (also after load issue)

    float tT = 0.f, tF = 0.f, tC = 0.f, tFA = 0.f;

#pragma unroll
    for (int r = 0; r < RPW; ++r) {      // fully unrolled -> static buf index
        float4* cur = (r & 1) ? Bv : A;
        float4* nxt = (r & 1) ? A  : Bv;

        // issue next row's loads BEFORE consuming current row
        if (r + 1 < RPW) {
            const float4* __restrict__ rp = tok4 + (size_t)(row0 + r + 1) * HW4;
#pragma unroll
            for (int u = 0; u < 16; ++u)
                nxt[u] = rp[u * 64 + lane];
        }
        // keep the prefetch cluster above the compute
        __builtin_amdgcn_sched_barrier(0);

        float s0 = 0.f, s1 = 0.f, d0 = 0.f, d1 = 0.f;
#pragma unroll
        for (int u = 0; u < 16; u += 2) {
            float4 pa = pj_lds[u * 64 + lane];
            float4 pb = pj_lds[(u + 1) * 64 + lane];
            s0 += cur[u].x + cur[u].y + cur[u].z + cur[u].w;
            d0 += cur[u].x * pa.x + cur[u].y * pa.y + cur[u].z * pa.z + cur[u].w * pa.w;
            s1 += cur[u+1].x + cur[u+1].y + cur[u+1].z + cur[u+1].w;
            d1 += cur[u+1].x * pb.x + cur[u+1].y * pb.y + cur[u+1].z * pb.z + cur[u+1].w * pb.w;
        }
        float s = s0 + s1, d = d0 + d1;
        float pi = pi_r[r];
        tT  += s;
        tF  += pi * s;
        tC  += d;
        tFA += pi * d;
    }

    // wave (64-lane) reduce
    for (int off = 32; off > 0; off >>= 1) {
        tT  += __shfl_down(tT,  off);
        tF  += __shfl_down(tF,  off);
        tC  += __shfl_down(tC,  off);
        tFA += __shfl_down(tFA, off);
    }

    if (lane == 0) {
        sm[wave][0] = (double)tT;
        sm[wave][1] = (double)tF;
        sm[wave][2] = (double)tC;
        sm[wave][3] = (double)tFA;
    }
    __syncthreads();

    if (threadIdx.x == 0) {
        D4 p;
        p.t  = sm[0][0] + sm[1][0] + sm[2][0] + sm[3][0];
        p.f  = sm[0][1] + sm[1][1] + sm[2][1] + sm[3][1];
        p.c  = sm[0][2] + sm[1][2] + sm[2][2] + sm[3][2];
        p.fa = sm[0][3] + sm[1][3] + sm[2][3] + sm[3][3];
        part[bid] = p;               // plain store — no atomics
    }
}

__global__ __launch_bounds__(256) void gsa_final(
    const D4* __restrict__ part, float* __restrict__ out)
{
    const double2* __restrict__ p2 = (const double2*)part;  // [NBLK*2]

    double aT = 0.0, aF = 0.0, aC = 0.0, aFA = 0.0;
    for (int k = threadIdx.x; k < NBLK; k += 256) {
        double2 lo = p2[k * 2 + 0];   // {t, f}
        double2 hi = p2[k * 2 + 1];   // {c, fa}
        aT += lo.x; aF += lo.y; aC += hi.x; aFA += hi.y;
    }

    for (int off = 32; off > 0; off >>= 1) {
        aT  += __shfl_down(aT,  off);
        aF  += __shfl_down(aF,  off);
        aC  += __shfl_down(aC,  off);
        aFA += __shfl_down(aFA, off);
    }

    __shared__ double sm[4][4];
    const int wave = threadIdx.x >> 6;
    const int lane = threadIdx.x & 63;
    if (lane == 0) {
        sm[wave][0] = aT; sm[wave][1] = aF;
        sm[wave][2] = aC; sm[wave][3] = aFA;
    }
    __syncthreads();

    if (threadIdx.x == 0) {
        double T   = sm[0][0] + sm[1][0] + sm[2][0] + sm[3][0];
        double sf  = sm[0][1] + sm[1][1] + sm[2][1] + sm[3][1];
        double sc  = sm[0][2] + sm[1][2] + sm[2][2] + sm[3][2];
        double sfa = sm[0][3] + sm[1][3] + sm[2][3] + sm[3][3];
        double sb  = T - sf;
        double sbb = T - sf - sc + sfa;
        out[0] = (float)(2.0 - sfa / sf - sbb / sb);
    }
}

extern "C" void kernel_launch(void* const* d_in, const int* in_sizes, int n_in,
                              void* d_out, int out_size, void* d_ws, size_t ws_size,
                              hipStream_t stream)
{
    const float* pred  = (const float*)d_in[0];
    const float* token = (const float*)d_in[1];
    float* out  = (float*)d_out;
    D4*    part = (D4*)d_ws;         // 512 * 32 B = 16 KB scratch

    // stage 1: persistent waves, 4 rows each, double-buffered prefetch
    gsa_partial<<<NBLK, 256, 0, stream>>>(pred, token, part);
    // stage 2: deterministic fixed-order reduction + scalar epilogue
    gsa_final<<<1, 256, 0, stream>>>(part, out);
}